// Round 2
// baseline (89.275 us; speedup 1.0000x reference)
//
#include <hip/hip_runtime.h>

constexpr int STRU = 68;   // row stride in u32 (272 B; rows 16B-aligned)

typedef short v8s __attribute__((ext_vector_type(8)));
typedef float v4f __attribute__((ext_vector_type(4)));

// fp32 -> packed (bf16_hi << 16) | bf16_lo. hi = truncated, lo = Dekker remainder
// rounded half-up. Reconstruction error ~2^-17 relative.
__device__ __forceinline__ unsigned packhl(float x) {
    unsigned xb = __builtin_bit_cast(unsigned, x);
    unsigned hb = xb & 0xffff0000u;
    float lof = x - __builtin_bit_cast(float, hb);           // exact
    unsigned lb = __builtin_bit_cast(unsigned, lof) + 0x8000u;
    return __builtin_amdgcn_perm(xb, lb, 0x07060302u);       // [hi16(xb) | hi16(lb)]
}

__device__ __forceinline__ float unpackf(unsigned v) {
    float h = __builtin_bit_cast(float, v & 0xffff0000u);
    float l = __builtin_bit_cast(float, v << 16);
    return h + l;
}

// load 8 packed u32 (one MFMA k-fragment of a row) -> hi/lo bf16x8
__device__ __forceinline__ void load_frag(const unsigned* p, v8s& hi, v8s& lo) {
    uint4 a = *(const uint4*)p;
    uint4 b = *(const uint4*)(p + 4);
    uint4 hw, lw;
    hw.x = __builtin_amdgcn_perm(a.y, a.x, 0x07060302u);
    hw.y = __builtin_amdgcn_perm(a.w, a.z, 0x07060302u);
    hw.z = __builtin_amdgcn_perm(b.y, b.x, 0x07060302u);
    hw.w = __builtin_amdgcn_perm(b.w, b.z, 0x07060302u);
    lw.x = __builtin_amdgcn_perm(a.y, a.x, 0x05040100u);
    lw.y = __builtin_amdgcn_perm(a.w, a.z, 0x05040100u);
    lw.z = __builtin_amdgcn_perm(b.y, b.x, 0x05040100u);
    lw.w = __builtin_amdgcn_perm(b.w, b.z, 0x05040100u);
    hi = __builtin_bit_cast(v8s, hw);
    lo = __builtin_bit_cast(v8s, lw);
}

#define MFMA __builtin_amdgcn_mfma_f32_16x16x32_bf16

// ---- 64x64 matmul, 8 waves/head, 2 tiles/wave: compute phase ----
// acc = P * Q^T for this wave's two 16x16 tiles. htid in [0,512).
__device__ __forceinline__ void mm_compute(const unsigned* __restrict__ P,
                                           const unsigned* __restrict__ Q,
                                           int htid, v4f acc[2]) {
    const int lane = htid & 63, w = htid >> 6;
    const int nh = lane & 15, qh = lane >> 4;
    const int tr = w >> 1, tc0 = (w & 1) << 1;   // tiles (tr,tc0),(tr,tc0+1)
    acc[0] = v4f{0, 0, 0, 0};
    acc[1] = v4f{0, 0, 0, 0};
    #pragma unroll
    for (int kk = 0; kk < 2; ++kk) {
        const int kc = kk * 32 + qh * 8;
        v8s ph, pl, q0h, q0l, q1h, q1l;
        load_frag(P + (tr * 16 + nh) * STRU + kc, ph, pl);
        load_frag(Q + (tc0 * 16 + nh) * STRU + kc, q0h, q0l);
        load_frag(Q + ((tc0 + 1) * 16 + nh) * STRU + kc, q1h, q1l);
        acc[0] = MFMA(ph, q0h, acc[0], 0, 0, 0);
        acc[0] = MFMA(ph, q0l, acc[0], 0, 0, 0);
        acc[0] = MFMA(pl, q0h, acc[0], 0, 0, 0);
        acc[1] = MFMA(ph, q1h, acc[1], 0, 0, 0);
        acc[1] = MFMA(ph, q1l, acc[1], 0, 0, 0);
        acc[1] = MFMA(pl, q1h, acc[1], 0, 0, 0);
    }
}

// ---- write phase. MODE 0: packed->D. 1: +I, packed->D. 2: fp32->G.
// MODE 3: packed->D AND transposed packed->DT. 4: ca*v->D; ca*v+I->DT.
// MODE 5: t=unpack(R); ca*t-I+cb*v->D; ca*t-I-cb*v->DT. ----
template<int MODE>
__device__ __forceinline__ void mm_write(const v4f acc[2],
                                         unsigned* D, unsigned* DT, float* G,
                                         const unsigned* R, float ca, float cb,
                                         int htid) {
    const int lane = htid & 63, w = htid >> 6;
    const int nh = lane & 15, qh = lane >> 4;
    const int tr = w >> 1, tc0 = (w & 1) << 1;
    const int row0 = tr * 16 + qh * 4;
    #pragma unroll
    for (int c = 0; c < 2; ++c) {
        const int col = (tc0 + c) * 16 + nh;
        if constexpr (MODE == 2) {
            #pragma unroll
            for (int e = 0; e < 4; ++e) G[(row0 + e) * 64 + col] = acc[c][e];
        } else if constexpr (MODE == 0) {
            #pragma unroll
            for (int e = 0; e < 4; ++e)
                D[(row0 + e) * STRU + col] = packhl(acc[c][e]);
        } else if constexpr (MODE == 1) {
            #pragma unroll
            for (int e = 0; e < 4; ++e) {
                float v = acc[c][e] + ((row0 + e) == col ? 1.0f : 0.0f);
                D[(row0 + e) * STRU + col] = packhl(v);
            }
        } else if constexpr (MODE == 3) {
            uint4 tp;
            #pragma unroll
            for (int e = 0; e < 4; ++e) {
                unsigned pk = packhl(acc[c][e]);
                D[(row0 + e) * STRU + col] = pk;
                ((unsigned*)&tp)[e] = pk;
            }
            *(uint4*)&DT[col * STRU + row0] = tp;   // DT[col][row0..row0+3]
        } else if constexpr (MODE == 4) {
            #pragma unroll
            for (int e = 0; e < 4; ++e) {
                float dv = ca * acc[c][e];
                float dg = ((row0 + e) == col) ? 1.0f : 0.0f;
                D[(row0 + e) * STRU + col]  = packhl(dv);
                DT[(row0 + e) * STRU + col] = packhl(dv + dg);
            }
        } else if constexpr (MODE == 5) {
            #pragma unroll
            for (int e = 0; e < 4; ++e) {
                float t  = unpackf(R[(row0 + e) * STRU + col]);
                float dg = ((row0 + e) == col) ? 1.0f : 0.0f;
                float base = ca * t - dg;
                float sv   = cb * acc[c][e];
                D[(row0 + e) * STRU + col]  = packhl(base + sv);
                DT[(row0 + e) * STRU + col] = packhl(base - sv);
            }
        }
    }
}

// Krylov doubling, compute phase: acc = (rows j<k of Xt) * M^T for this wave's
// unit. Garbage in source rows >= k only feeds discarded output rows.
__device__ __forceinline__ bool dbl_compute(const unsigned* __restrict__ Xt,
                                            const unsigned* __restrict__ M,
                                            int k, int htid, v4f& acc) {
    const int lane = htid & 63, w = htid >> 6;
    const int nh = lane & 15, qh = lane >> 4;
    const int nt = (k + 15) >> 4;
    if (w >= 4 * nt) return false;
    const int t = w >> 2, cb = w & 3;
    acc = v4f{0, 0, 0, 0};
    #pragma unroll
    for (int kk = 0; kk < 2; ++kk) {
        const int kc = kk * 32 + qh * 8;
        v8s ph, pl, mh, ml;
        load_frag(Xt + (t * 16 + nh) * STRU + kc, ph, pl);
        load_frag(M + (cb * 16 + nh) * STRU + kc, mh, ml);
        acc = MFMA(ph, mh, acc, 0, 0, 0);
        acc = MFMA(ph, ml, acc, 0, 0, 0);
        acc = MFMA(pl, mh, acc, 0, 0, 0);
    }
    return true;
}

__device__ __forceinline__ void dbl_write(const v4f& acc, unsigned* Xt, int k,
                                          int htid) {
    const int lane = htid & 63, w = htid >> 6;
    const int nh = lane & 15, qh = lane >> 4;
    const int t = w >> 2, cb = w & 3;
    #pragma unroll
    for (int e = 0; e < 4; ++e) {
        const int j = t * 16 + qh * 4 + e;
        if (j < k) Xt[(k + j) * STRU + cb * 16 + nh] = packhl(acc[e]);
    }
}

// 2 heads per block, 8 waves each. 4 LDS buffers/head via in-place squaring
// (compute -> barrier -> write). Buffer lifetimes:
//   b0: S -> (after M5) Ut     b1: D~ -> (M3) T -> (after M5) Vt
//   b2: T0=I+D -> (M5) X       b3: V=I+D^2 -> (M5) XT
__launch_bounds__(1024)
__global__ void krylov_kernel(const float* __restrict__ A,
                              const float* __restrict__ Bv,
                              const float* __restrict__ Cv,
                              const float* __restrict__ logdt,
                              float* __restrict__ out)
{
    const int tid  = threadIdx.x;
    const int hd   = tid >> 9;          // head slot 0/1
    const int htid = tid & 511;         // thread id within head
    const int h    = blockIdx.x * 2 + hd;
    const int lane = htid & 63;

    __shared__ __align__(16) unsigned SM[8][64 * STRU];
    __shared__ float Bl[2][64];

    unsigned* b0 = SM[hd * 4 + 0];
    unsigned* b1 = SM[hd * 4 + 1];
    unsigned* b2 = SM[hd * 4 + 2];
    unsigned* b3 = SM[hd * 4 + 3];

    const float dt = expf(logdt[h]);
    const float c  = 0.5f * dt;
    const float al = 1.0f + 0.5f * c;
    const float sd = -(c * c) / (al * al);   // D~ = sd * (S S^T)
    const float c1 = 2.0f / al;              // X = c1*T + c2*SH - I
    const float c2 = 2.0f * c / (al * al);

    const float* Ah = A + (size_t)h * 4096;

    // ---- P0: pack S = A + 0.5I into b0; B -> Bl ----
    for (int idx = htid; idx < 1024; idx += 512) {
        const int r = idx >> 4, c0 = (idx & 15) * 4;
        float4 v = *(const float4*)(Ah + idx * 4);
        if (r == c0 + 0) v.x += 0.5f;
        if (r == c0 + 1) v.y += 0.5f;
        if (r == c0 + 2) v.z += 0.5f;
        if (r == c0 + 3) v.w += 0.5f;
        uint4 pk = make_uint4(packhl(v.x), packhl(v.y), packhl(v.z), packhl(v.w));
        *(uint4*)&b0[r * STRU + c0] = pk;
    }
    if (htid < 64) Bl[hd][htid] = Bv[h * 64 + htid];
    __syncthreads();

    v4f acc[2];

    // ---- M1: S*S^T -> D~ = sd*acc (b1), T0 = D~ + I (b2) ----
    mm_compute(b0, b0, htid, acc);
    mm_write<4>(acc, b1, b2, nullptr, nullptr, sd, 0.f, htid);
    __syncthreads();
    // ---- M2: V = D~^2 + I -> b3  (D~ symmetric) ----
    mm_compute(b1, b1, htid, acc);
    mm_write<1>(acc, b3, nullptr, nullptr, nullptr, 0.f, 0.f, htid);
    __syncthreads();
    // ---- M3 (Estrin): T = (I+D~)(I+D~^2) = T0 * V -> b1 (D~ dead; V sym) ----
    mm_compute(b2, b3, htid, acc);
    mm_write<0>(acc, b1, nullptr, nullptr, nullptr, 0.f, 0.f, htid);
    __syncthreads();
    // ---- M5: SH = S*T; X = c1*T + c2*SH - I (b2), XT = c1*T - c2*SH - I (b3) ----
    mm_compute(b0, b1, htid, acc);
    mm_write<5>(acc, b2, b3, nullptr, b1, c1, c2, htid);
    __syncthreads();

    // ---- seed: Vt row0 = dB = (dt/2)(X*B + B) -> b1; Ut row0 = C -> b0 ----
    if ((htid >> 6) == 0) {
        const unsigned* Xr = b2 + lane * STRU;
        float a2 = 0.0f;
        #pragma unroll
        for (int m4 = 0; m4 < 16; ++m4) {
            uint4 xv = *(const uint4*)(Xr + 4 * m4);
            float4 b4 = *(const float4*)&Bl[hd][4 * m4];
            a2 += unpackf(xv.x) * b4.x + unpackf(xv.y) * b4.y
                + unpackf(xv.z) * b4.z + unpackf(xv.w) * b4.w;
        }
        b1[lane] = packhl(c * (a2 + Bl[hd][lane]));
    } else if (htid < 128) {
        b0[htid - 64] = packhl(Cv[h * 64 + (htid - 64)]);
    }
    __syncthreads();

    // ---- ladder A: s=0..5: in-place dual-square X(b2)/XT(b3); double Vt(b1) ----
    #pragma unroll 1
    for (int s = 0; s < 6; ++s) {
        const int k = 1 << s;
        mm_compute(b2, b3, htid, acc);
        v4f da; const bool dv = dbl_compute(b1, b2, k, htid, da);
        __syncthreads();                       // all reads of old X/XT done
        mm_write<3>(acc, b2, b3, nullptr, nullptr, 0.f, 0.f, htid);
        if (dv) dbl_write(da, b1, k, htid);
        __syncthreads();
    }
    // b2 = E = dA^64, b3 = E^T

    // ---- ladder B: s=0..4: double Ut(b0) with XT = (E^(2^s))^T; in-place square ----
    #pragma unroll 1
    for (int s = 0; s < 5; ++s) {
        const int k = 1 << s;
        mm_compute(b2, b3, htid, acc);
        v4f da; const bool dv = dbl_compute(b0, b3, k, htid, da);
        __syncthreads();
        mm_write<3>(acc, b2, b3, nullptr, nullptr, 0.f, 0.f, htid);
        if (dv) dbl_write(da, b0, k, htid);
        __syncthreads();
    }
    // s=5: dbl only (writes rows >=32, reads rows <32: no hazard, single phase)
    {
        v4f da; const bool dv = dbl_compute(b0, b3, 32, htid, da);
        if (dv) dbl_write(da, b0, 32, htid);
        __syncthreads();
    }

    // ---- final: out[h][64q + r] = sum_n Ut[q][n] * Vt[r][n] ----
    mm_compute(b0, b1, htid, acc);
    mm_write<2>(acc, nullptr, nullptr, out + (size_t)h * 4096, nullptr,
                0.f, 0.f, htid);
}

extern "C" void kernel_launch(void* const* d_in, const int* in_sizes, int n_in,
                              void* d_out, int out_size, void* d_ws, size_t ws_size,
                              hipStream_t stream) {
    const float* A  = (const float*)d_in[0];
    const float* B  = (const float*)d_in[1];
    const float* C  = (const float*)d_in[2];
    const float* ld = (const float*)d_in[3];
    float* out = (float*)d_out;
    const int H = in_sizes[3];   // 256 heads
    krylov_kernel<<<H / 2, 1024, 0, stream>>>(A, B, C, ld, out);
}

// Round 3
// 78.359 us; speedup vs baseline: 1.1393x; 1.1393x over previous
//
#include <hip/hip_runtime.h>

constexpr int STRU = 68;   // row stride in u32 (272 B; rows 16B-aligned)

typedef short v8s __attribute__((ext_vector_type(8)));
typedef float v4f __attribute__((ext_vector_type(4)));

// fp32 -> packed (bf16_hi << 16) | bf16_lo. hi = truncated, lo = Dekker remainder
// rounded half-up. Reconstruction error ~2^-17 relative.
__device__ __forceinline__ unsigned packhl(float x) {
    unsigned xb = __builtin_bit_cast(unsigned, x);
    unsigned hb = xb & 0xffff0000u;
    float lof = x - __builtin_bit_cast(float, hb);           // exact
    unsigned lb = __builtin_bit_cast(unsigned, lof) + 0x8000u;
    return __builtin_amdgcn_perm(xb, lb, 0x07060302u);       // [hi16(xb) | hi16(lb)]
}

__device__ __forceinline__ float unpackf(unsigned v) {
    float h = __builtin_bit_cast(float, v & 0xffff0000u);
    float l = __builtin_bit_cast(float, v << 16);
    return h + l;
}

// load 8 packed u32 (one MFMA k-fragment of a row) -> hi/lo bf16x8
__device__ __forceinline__ void load_frag(const unsigned* p, v8s& hi, v8s& lo) {
    uint4 a = *(const uint4*)p;
    uint4 b = *(const uint4*)(p + 4);
    uint4 hw, lw;
    hw.x = __builtin_amdgcn_perm(a.y, a.x, 0x07060302u);
    hw.y = __builtin_amdgcn_perm(a.w, a.z, 0x07060302u);
    hw.z = __builtin_amdgcn_perm(b.y, b.x, 0x07060302u);
    hw.w = __builtin_amdgcn_perm(b.w, b.z, 0x07060302u);
    lw.x = __builtin_amdgcn_perm(a.y, a.x, 0x05040100u);
    lw.y = __builtin_amdgcn_perm(a.w, a.z, 0x05040100u);
    lw.z = __builtin_amdgcn_perm(b.y, b.x, 0x05040100u);
    lw.w = __builtin_amdgcn_perm(b.w, b.z, 0x05040100u);
    hi = __builtin_bit_cast(v8s, hw);
    lo = __builtin_bit_cast(v8s, lw);
}

#define MFMA __builtin_amdgcn_mfma_f32_16x16x32_bf16

// D = P * Q^T (64x64, packed LDS operands), 8 waves, 2 tiles/wave.
// MODE 0: packed->D. 1: +I, packed->D. 2: fp32->G (global, row stride 64).
// MODE 3: packed->D AND transposed packed->DT (b128 per tile).
// MODE 4: ca*v -> D; ca*v + I -> DT  (both normal orientation).
// MODE 5: t=unpack(R[row][col]); ca*t - I + cb*v -> D; ca*t - I - cb*v -> DT.
template<int MODE>
__device__ __forceinline__ void mm64(const unsigned* __restrict__ P,
                                     const unsigned* __restrict__ Q,
                                     unsigned* D, unsigned* DT, float* G,
                                     const unsigned* R, float ca, float cb,
                                     int tid) {
    const int lane = tid & 63, w = tid >> 6;
    const int nh = lane & 15, qh = lane >> 4;
    const int tr = w >> 1, tc0 = (w & 1) << 1;   // wave: tiles (tr,tc0),(tr,tc0+1)
    v4f acc[2] = {v4f{0,0,0,0}, v4f{0,0,0,0}};
    #pragma unroll
    for (int kk = 0; kk < 2; ++kk) {
        const int kc = kk * 32 + qh * 8;
        v8s ph, pl, q0h, q0l, q1h, q1l;
        load_frag(P + (tr * 16 + nh) * STRU + kc, ph, pl);
        load_frag(Q + (tc0 * 16 + nh) * STRU + kc, q0h, q0l);
        load_frag(Q + ((tc0 + 1) * 16 + nh) * STRU + kc, q1h, q1l);
        acc[0] = MFMA(ph, q0h, acc[0], 0, 0, 0);
        acc[0] = MFMA(ph, q0l, acc[0], 0, 0, 0);
        acc[0] = MFMA(pl, q0h, acc[0], 0, 0, 0);
        acc[1] = MFMA(ph, q1h, acc[1], 0, 0, 0);
        acc[1] = MFMA(ph, q1l, acc[1], 0, 0, 0);
        acc[1] = MFMA(pl, q1h, acc[1], 0, 0, 0);
    }
    const int row0 = tr * 16 + qh * 4;
    #pragma unroll
    for (int c = 0; c < 2; ++c) {
        const int col = (tc0 + c) * 16 + nh;
        if constexpr (MODE == 2) {
            #pragma unroll
            for (int e = 0; e < 4; ++e) G[(row0 + e) * 64 + col] = acc[c][e];
        } else if constexpr (MODE == 0) {
            #pragma unroll
            for (int e = 0; e < 4; ++e)
                D[(row0 + e) * STRU + col] = packhl(acc[c][e]);
        } else if constexpr (MODE == 1) {
            #pragma unroll
            for (int e = 0; e < 4; ++e) {
                float v = acc[c][e] + ((row0 + e) == col ? 1.0f : 0.0f);
                D[(row0 + e) * STRU + col] = packhl(v);
            }
        } else if constexpr (MODE == 3) {
            uint4 tp;
            #pragma unroll
            for (int e = 0; e < 4; ++e) {
                unsigned pk = packhl(acc[c][e]);
                D[(row0 + e) * STRU + col] = pk;
                ((unsigned*)&tp)[e] = pk;
            }
            *(uint4*)&DT[col * STRU + row0] = tp;   // DT[col][row0..row0+3]
        } else if constexpr (MODE == 4) {
            #pragma unroll
            for (int e = 0; e < 4; ++e) {
                float dv = ca * acc[c][e];
                float dg = ((row0 + e) == col) ? 1.0f : 0.0f;
                D[(row0 + e) * STRU + col]  = packhl(dv);
                DT[(row0 + e) * STRU + col] = packhl(dv + dg);
            }
        } else if constexpr (MODE == 5) {
            #pragma unroll
            for (int e = 0; e < 4; ++e) {
                float t  = unpackf(R[(row0 + e) * STRU + col]);
                float dg = ((row0 + e) == col) ? 1.0f : 0.0f;
                float base = ca * t - dg;
                float sv   = cb * acc[c][e];
                D[(row0 + e) * STRU + col]  = packhl(base + sv);
                DT[(row0 + e) * STRU + col] = packhl(base - sv);
            }
        }
    }
}

// Krylov doubling: Xt rows [k,2k) <- (rows j<k of Xt) * M^T.
// Garbage in source rows >= k only feeds discarded output rows (MFMA row m of D
// depends only on row m of A-operand). 8 waves: unit = (row tile, col block).
__device__ __forceinline__ void dbl64(unsigned* Xt, const unsigned* M, int k, int tid) {
    const int lane = tid & 63, w = tid >> 6;
    const int nh = lane & 15, qh = lane >> 4;
    const int nt = (k + 15) >> 4;
    if (w < 4 * nt) {
        const int t = w >> 2, cb = w & 3;
        v4f acc = {0, 0, 0, 0};
        #pragma unroll
        for (int kk = 0; kk < 2; ++kk) {
            const int kc = kk * 32 + qh * 8;
            v8s ph, pl, mh, ml;
            load_frag(Xt + (t * 16 + nh) * STRU + kc, ph, pl);
            load_frag(M + (cb * 16 + nh) * STRU + kc, mh, ml);
            acc = MFMA(ph, mh, acc, 0, 0, 0);
            acc = MFMA(ph, ml, acc, 0, 0, 0);
            acc = MFMA(pl, mh, acc, 0, 0, 0);
        }
        #pragma unroll
        for (int e = 0; e < 4; ++e) {
            const int j = t * 16 + qh * 4 + e;
            if (j < k) Xt[(k + j) * STRU + cb * 16 + nh] = packhl(acc[e]);
        }
    }
}

__launch_bounds__(512)
__global__ void krylov_kernel(const float* __restrict__ A,
                              const float* __restrict__ Bv,
                              const float* __restrict__ Cv,
                              const float* __restrict__ logdt,
                              float* __restrict__ out)
{
    const int h    = blockIdx.x;
    const int tid  = threadIdx.x;
    const int lane = tid & 63;
    const int w    = tid >> 6;

    __shared__ __align__(16) unsigned SM[6][64 * STRU];
    __shared__ float Bl[64];

    const float dt = expf(logdt[h]);
    const float c  = 0.5f * dt;
    const float al = 1.0f + 0.5f * c;
    const float sd = -(c * c) / (al * al);   // D~ = sd * (S S^T)
    const float c1 = 2.0f / al;              // X = c1*T + c2*SH - I
    const float c2 = 2.0f * c / (al * al);

    const float* Ah = A + (size_t)h * 4096;

    // ---- P0: pack S = A + 0.5I into SM0; B -> Bl; Ut row0 = C -> SM5 ----
    for (int idx = tid; idx < 1024; idx += 512) {
        const int r = idx >> 4, c0 = (idx & 15) * 4;
        float4 v = *(const float4*)(Ah + idx * 4);
        if (r == c0 + 0) v.x += 0.5f;
        if (r == c0 + 1) v.y += 0.5f;
        if (r == c0 + 2) v.z += 0.5f;
        if (r == c0 + 3) v.w += 0.5f;
        uint4 pk = make_uint4(packhl(v.x), packhl(v.y), packhl(v.z), packhl(v.w));
        *(uint4*)&SM[0][r * STRU + c0] = pk;
    }
    if (tid < 64) Bl[tid] = Bv[h * 64 + tid];
    else if (tid < 128) SM[5][tid - 64] = packhl(Cv[h * 64 + (tid - 64)]);
    __syncthreads();

    // ---- M1: S*S^T -> D~ = sd*acc (SM1), T0 = D~ + I (SM2) ----
    mm64<4>(SM[0], SM[0], SM[1], SM[2], nullptr, nullptr, sd, 0.f, tid);
    __syncthreads();
    // ---- M2 (Estrin): V = D~^2 + I -> SM3  (D~ symmetric) ----
    mm64<1>(SM[1], SM[1], SM[3], nullptr, nullptr, nullptr, 0.f, 0.f, tid);
    __syncthreads();
    // ---- M3 (Estrin): T = (I+D~)(I+D~^2) = T0 * V -> SM1 (V symmetric; D~ dead) ----
    mm64<0>(SM[2], SM[3], SM[1], nullptr, nullptr, nullptr, 0.f, 0.f, tid);
    __syncthreads();
    // ---- M5: SH = S*T; X = c1*T + c2*SH - I (SM2), XT = c1*T - c2*SH - I (SM3) ----
    mm64<5>(SM[0], SM[1], SM[2], SM[3], nullptr, SM[1], c1, c2, tid);
    __syncthreads();

    // ---- seed: Vt row0 = dB = (dt/2)(X*B + B) ----
    if (w == 0) {
        const unsigned* Xr = SM[2] + lane * STRU;
        float acc = 0.0f;
        #pragma unroll
        for (int m4 = 0; m4 < 16; ++m4) {
            uint4 xv = *(const uint4*)(Xr + 4 * m4);
            float4 b4 = *(const float4*)&Bl[4 * m4];
            acc += unpackf(xv.x) * b4.x + unpackf(xv.y) * b4.y
                 + unpackf(xv.z) * b4.z + unpackf(xv.w) * b4.w;
        }
        SM[4][lane] = packhl(c * (acc + Bl[lane]));
    }
    __syncthreads();

    // ---- ladder A: s=0..5: dual-square X -> X^2, X^2T; double Vt with X ----
    // X=SM2, XT=SM3; ping-pong with SM0 (S dead), SM1 (T dead).
    unsigned *bX = SM[2], *bXT = SM[3], *bN = SM[0], *bNT = SM[1];
    #pragma unroll 1
    for (int s = 0; s < 6; ++s) {
        mm64<3>(bX, bXT, bN, bNT, nullptr, nullptr, 0.f, 0.f, tid);
        dbl64(SM[4], bX, 1 << s, tid);
        __syncthreads();
        unsigned* t0 = bX;  bX  = bN;  bN  = t0;
        t0 = bXT; bXT = bNT; bNT = t0;
    }
    // bX = E = dA^64, bXT = E^T

    // ---- ladder B: s=0..5: double Ut with XT = (E^T)^(2^s); dual-square (s<5) ----
    #pragma unroll 1
    for (int s = 0; s < 6; ++s) {
        if (s < 5) mm64<3>(bX, bXT, bN, bNT, nullptr, nullptr, 0.f, 0.f, tid);
        dbl64(SM[5], bXT, 1 << s, tid);
        __syncthreads();
        if (s < 5) {
            unsigned* t0 = bX;  bX  = bN;  bN  = t0;
            t0 = bXT; bXT = bNT; bNT = t0;
        }
    }

    // ---- final: out[h][64q + r] = sum_n Ut[q][n] * Vt[r][n] ----
    mm64<2>(SM[5], SM[4], nullptr, nullptr, out + (size_t)h * 4096, nullptr,
            0.f, 0.f, tid);
}

extern "C" void kernel_launch(void* const* d_in, const int* in_sizes, int n_in,
                              void* d_out, int out_size, void* d_ws, size_t ws_size,
                              hipStream_t stream) {
    const float* A  = (const float*)d_in[0];
    const float* B  = (const float*)d_in[1];
    const float* C  = (const float*)d_in[2];
    const float* ld = (const float*)d_in[3];
    float* out = (float*)d_out;
    const int H = in_sizes[3];   // 256 heads
    krylov_kernel<<<H, 512, 0, stream>>>(A, B, C, ld, out);
}